// Round 5
// baseline (182.102 us; speedup 1.0000x reference)
//
#include <hip/hip_runtime.h>
#include <stdint.h>

typedef unsigned short u16;
typedef __attribute__((ext_vector_type(8))) short bf16x8;
typedef __attribute__((ext_vector_type(4))) float f32x4;

__device__ __forceinline__ float bf2f(u16 u){
  union { uint32_t i; float f; } v; v.i = ((uint32_t)u) << 16; return v.f;
}
__device__ __forceinline__ u16 f2bf(float f){
  union { float fl; uint32_t i; } v; v.fl = f;
  uint32_t r = v.i + 0x7FFFu + ((v.i >> 16) & 1u);
  return (u16)(r >> 16);
}
__device__ __forceinline__ uint32_t cvt_pk_bf16(float lo, float hi){
  uint32_t r;
  asm("v_cvt_pk_bf16_f32 %0, %1, %2" : "=v"(r) : "v"(lo), "v"(hi));
  return r;
}
__device__ __forceinline__ f32x4 mfma16(bf16x8 a, bf16x8 b, f32x4 c){
  return __builtin_amdgcn_mfma_f32_16x16x32_bf16(a, b, c, 0, 0, 0);
}
// async global->LDS, 16 B per lane; LDS dest is wave-uniform base + lane*16
__device__ __forceinline__ void gload16(const u16* g, u16* l){
  __builtin_amdgcn_global_load_lds((const __attribute__((address_space(1))) void*)g,
                                   (__attribute__((address_space(3))) void*)l, 16, 0, 0);
}

// ---------------- elementwise convert f32 -> bf16 (with scale fold) ----------------
__global__ __launch_bounds__(256) void k_conv_bf(const float* __restrict__ in, u16* __restrict__ out, int n, float scale){
  int i = (blockIdx.x * 256 + threadIdx.x) * 4;
  if (i >= n) return;
  float4 v = *(const float4*)(in + i);
  ushort4 o; o.x=f2bf(v.x*scale); o.y=f2bf(v.y*scale); o.z=f2bf(v.z*scale); o.w=f2bf(v.w*scale);
  *(ushort4*)(out + i) = o;
}

// ---------- transpose + convert: in[R][C] f32 -> out[C][R] bf16 ----------
__global__ __launch_bounds__(256) void k_transp(const float* __restrict__ in, u16* __restrict__ out, int R, int C){
  __shared__ u16 tile[64][68];
  int c0 = blockIdx.x * 64, r0 = blockIdx.y * 64;
  int tr = threadIdx.x >> 4;           // 0..15
  int tc = (threadIdx.x & 15) * 4;     // 0..60
  for (int rr = 0; rr < 4; rr++){
    int r = rr * 16 + tr;
    float4 v = *(const float4*)(in + (size_t)(r0 + r) * C + c0 + tc);
    ushort4 o; o.x=f2bf(v.x); o.y=f2bf(v.y); o.z=f2bf(v.z); o.w=f2bf(v.w);
    *(ushort4*)&tile[r][tc] = o;
  }
  __syncthreads();
  for (int rr = 0; rr < 4; rr++){
    int oc = rr * 16 + tr;             // original col = out row
    ushort4 o;
    o.x = tile[tc+0][oc]; o.y = tile[tc+1][oc]; o.z = tile[tc+2][oc]; o.w = tile[tc+3][oc];
    *(ushort4*)(out + (size_t)(c0 + oc) * R + r0 + tc) = o;
  }
}

// ---------- transpose V part of qkv (bf16) -> vT[8*64][16384] ----------
__global__ __launch_bounds__(256) void k_transp_v(const u16* __restrict__ qkv, u16* __restrict__ vT){
  __shared__ u16 tile[64][68];
  int n0 = blockIdx.x * 64;            // n tile
  int c0 = blockIdx.y * 64;            // (h*64+d) tile
  int tr = threadIdx.x >> 4;
  int tc = (threadIdx.x & 15) * 4;
  for (int rr = 0; rr < 4; rr++){
    int r = rr * 16 + tr;
    ushort4 v = *(const ushort4*)(qkv + (size_t)(n0 + r) * 1536 + 1024 + c0 + tc);
    *(ushort4*)&tile[r][tc] = v;
  }
  __syncthreads();
  for (int rr = 0; rr < 4; rr++){
    int oc = rr * 16 + tr;
    ushort4 o;
    o.x = tile[tc+0][oc]; o.y = tile[tc+1][oc]; o.z = tile[tc+2][oc]; o.w = tile[tc+3][oc];
    *(ushort4*)(vT + (size_t)(c0 + oc) * 16384 + n0 + tc) = o;
  }
}

// ---------------- LayerNorm: x[16384][512] f32 -> xn bf16 ----------------
__global__ __launch_bounds__(128) void k_ln(const float* __restrict__ x, const float* __restrict__ g,
                                            const float* __restrict__ b, u16* __restrict__ xn){
  int row = blockIdx.x;
  int t = threadIdx.x;
  float4 v = *(const float4*)(x + (size_t)row * 512 + t * 4);
  float s = v.x + v.y + v.z + v.w;
  float q = v.x*v.x + v.y*v.y + v.z*v.z + v.w*v.w;
  for (int o = 32; o > 0; o >>= 1){ s += __shfl_down(s, o); q += __shfl_down(q, o); }
  __shared__ float red[4];
  if ((t & 63) == 0){ red[(t >> 6) * 2] = s; red[(t >> 6) * 2 + 1] = q; }
  __syncthreads();
  float mu  = (red[0] + red[2]) * (1.0f/512.0f);
  float var = (red[1] + red[3]) * (1.0f/512.0f) - mu * mu;
  float rs = rsqrtf(var + 1e-5f);
  float4 gv = *(const float4*)(g + t * 4);
  float4 bv = *(const float4*)(b + t * 4);
  ushort4 o;
  o.x = f2bf((v.x - mu) * rs * gv.x + bv.x);
  o.y = f2bf((v.y - mu) * rs * gv.y + bv.y);
  o.z = f2bf((v.z - mu) * rs * gv.z + bv.z);
  o.w = f2bf((v.w - mu) * rs * gv.w + bv.w);
  *(ushort4*)(xn + (size_t)row * 512 + t * 4) = o;
}

// ------- QKV GEMM (2-phase dbuf + gload_lds): C[16384][1536] = A * Bt^T ----------
__global__ __launch_bounds__(256) void k_gemm_qkv(const u16* __restrict__ A, const u16* __restrict__ Bt,
                                                  u16* __restrict__ C){
  __shared__ u16 aL[2][128 * 64];
  __shared__ u16 bL[2][128 * 64];
  int m0 = blockIdx.x * 128, n0 = blockIdx.y * 128;
  int t = threadIdx.x, w = t >> 6, l = t & 63;
  int wm = (w >> 1) * 64, wn = (w & 1) * 64;
  int lr = l & 15, kb0 = (l >> 4) * 8;
  const u16* gA = A  + (size_t)(m0 + w*32 + (l >> 3)) * 512 + (l & 7) * 8;
  const u16* gB = Bt + (size_t)(n0 + w*32 + (l >> 3)) * 512 + (l & 7) * 8;
  int ldsOff = (w*32) * 64;            // wave-uniform LDS base (lane*16B appended by HW)
  f32x4 acc[4][4];
  for (int i=0;i<4;i++) for (int j=0;j<4;j++) acc[i][j] = {0.f,0.f,0.f,0.f};

  auto stage = [&](int buf, int k0){
    #pragma unroll
    for (int i = 0; i < 4; i++){
      gload16(gA + k0 + (size_t)i*8*512, &aL[buf][ldsOff + i*8*64]);
      gload16(gB + k0 + (size_t)i*8*512, &bL[buf][ldsOff + i*8*64]);
    }
  };
  auto comp = [&](const u16* ab, const u16* bb){
    #pragma unroll
    for (int kk = 0; kk < 64; kk += 32){
      int kb = kb0 + kk;
      bf16x8 av[4], bv[4];
      #pragma unroll
      for (int mt=0;mt<4;mt++) av[mt] = *(const bf16x8*)&ab[(wm + mt*16 + lr)*64 + kb];
      #pragma unroll
      for (int nt=0;nt<4;nt++) bv[nt] = *(const bf16x8*)&bb[(wn + nt*16 + lr)*64 + kb];
      #pragma unroll
      for (int mt=0;mt<4;mt++)
        #pragma unroll
        for (int nt=0;nt<4;nt++)
          acc[mt][nt] = mfma16(av[mt], bv[nt], acc[mt][nt]);
    }
  };

  stage(0, 0);
  __syncthreads();                     // buf0 ready
  #pragma unroll
  for (int tk = 0; tk < 8; tk += 2){
    stage(1, (tk + 1) * 64);           // issue next while computing cur
    comp(&aL[0][0], &bL[0][0]);
    __syncthreads();                   // drain stage(1); buf0 free
    if (tk + 2 < 8) stage(0, (tk + 2) * 64);
    comp(&aL[1][0], &bL[1][0]);
    __syncthreads();                   // drain stage(0); buf1 free
  }

  int rr = (l >> 4) * 4, cc = l & 15;
  for (int mt=0;mt<4;mt++) for (int nt=0;nt<4;nt++)
    for (int j=0;j<4;j++){
      int r = m0 + wm + mt*16 + rr + j;
      int c = n0 + wn + nt*16 + cc;
      C[(size_t)r * 1536 + c] = f2bf(acc[mt][nt][j]);
    }
}

// ------- out GEMM (2-phase dbuf + gload_lds): y = A*Bt^T + bias + x (f32) ----------
__global__ __launch_bounds__(256) void k_gemm_out(const u16* __restrict__ A, const u16* __restrict__ Bt,
                                                  const float* __restrict__ x, const float* __restrict__ bias,
                                                  float* __restrict__ y){
  __shared__ u16 aL[2][128 * 64];
  __shared__ u16 bL[2][128 * 64];
  int m0 = blockIdx.x * 128, n0 = blockIdx.y * 128;
  int t = threadIdx.x, w = t >> 6, l = t & 63;
  int wm = (w >> 1) * 64, wn = (w & 1) * 64;
  int lr = l & 15, kb0 = (l >> 4) * 8;
  const u16* gA = A  + (size_t)(m0 + w*32 + (l >> 3)) * 512 + (l & 7) * 8;
  const u16* gB = Bt + (size_t)(n0 + w*32 + (l >> 3)) * 512 + (l & 7) * 8;
  int ldsOff = (w*32) * 64;
  f32x4 acc[4][4];
  for (int i=0;i<4;i++) for (int j=0;j<4;j++) acc[i][j] = {0.f,0.f,0.f,0.f};

  auto stage = [&](int buf, int k0){
    #pragma unroll
    for (int i = 0; i < 4; i++){
      gload16(gA + k0 + (size_t)i*8*512, &aL[buf][ldsOff + i*8*64]);
      gload16(gB + k0 + (size_t)i*8*512, &bL[buf][ldsOff + i*8*64]);
    }
  };
  auto comp = [&](const u16* ab, const u16* bb){
    #pragma unroll
    for (int kk = 0; kk < 64; kk += 32){
      int kb = kb0 + kk;
      bf16x8 av[4], bv[4];
      #pragma unroll
      for (int mt=0;mt<4;mt++) av[mt] = *(const bf16x8*)&ab[(wm + mt*16 + lr)*64 + kb];
      #pragma unroll
      for (int nt=0;nt<4;nt++) bv[nt] = *(const bf16x8*)&bb[(wn + nt*16 + lr)*64 + kb];
      #pragma unroll
      for (int mt=0;mt<4;mt++)
        #pragma unroll
        for (int nt=0;nt<4;nt++)
          acc[mt][nt] = mfma16(av[mt], bv[nt], acc[mt][nt]);
    }
  };

  stage(0, 0);
  __syncthreads();
  #pragma unroll
  for (int tk = 0; tk < 8; tk += 2){
    stage(1, (tk + 1) * 64);
    comp(&aL[0][0], &bL[0][0]);
    __syncthreads();
    if (tk + 2 < 8) stage(0, (tk + 2) * 64);
    comp(&aL[1][0], &bL[1][0]);
    __syncthreads();
  }

  int rr = (l >> 4) * 4, cc = l & 15;
  for (int mt=0;mt<4;mt++) for (int nt=0;nt<4;nt++)
    for (int j=0;j<4;j++){
      int r = m0 + wm + mt*16 + rr + j;
      int c = n0 + wn + nt*16 + cc;
      y[(size_t)r * 512 + c] = acc[mt][nt][j] + bias[c] + x[(size_t)r * 512 + c];
    }
}

// ---------------- agent aggregation partials (attn1 + agent_v, no-max softmax) ----
// 1024 blocks; swizzled so the 8 atile-blocks of one (h,chunk) share an XCD.
__global__ __launch_bounds__(256) void k_agent_agg(const u16* __restrict__ agbf, const u16* __restrict__ qkv,
                                                   const u16* __restrict__ vT,
                                                   float* __restrict__ nump, float* __restrict__ denp){
  int L = blockIdx.x;
  int g = (L >> 6) * 8 + (L & 7);      // group = h*16 + ch  (same K/V panel)
  int m = (L >> 3) & 7;                // atile
  int h = g >> 4, ch = g & 15, a0 = m * 64;

  __shared__ u16 ag[64][72];
  __shared__ u16 kt[64][72];
  __shared__ u16 vt[64][72];
  __shared__ u16 pt[64][72];
  int t = threadIdx.x, w = t >> 6, l = t & 63;

  for (int i = 0; i < 2; i++){
    int flat = t + 256 * i;
    int r = flat >> 3, c = (flat & 7) * 8;
    *(uint4*)&ag[r][c] = *(const uint4*)(agbf + (size_t)(h * 512 + a0 + r) * 64 + c);
  }

  bf16x8 ones;
  for (int i = 0; i < 8; i++) ones[i] = (short)0x3F80;

  f32x4 acc2[4];                       // C[a][d], wave owns d-stripe w*16
  for (int i=0;i<4;i++) acc2[i] = {0.f,0.f,0.f,0.f};
  f32x4 accd = {0.f,0.f,0.f,0.f};      // den[a], wave owns a-stripe w*16

  for (int sub = 0; sub < 16; sub++){
    int n0 = ch * 1024 + sub * 64;
    __syncthreads();                   // protect kt/vt/pt from previous readers
    {
      int flat = t;
      int r = flat >> 3, c = (flat & 7) * 8;
      *(uint4*)&kt[r][c] = *(const uint4*)(qkv + (size_t)(n0 + r) * 1536 + 512 + h * 64 + c);
      int flat2 = t + 256;
      int r2 = flat2 >> 3, c2 = (flat2 & 7) * 8;
      *(uint4*)&kt[r2][c2] = *(const uint4*)(qkv + (size_t)(n0 + r2) * 1536 + 512 + h * 64 + c2);
      *(uint4*)&vt[r][c]   = *(const uint4*)(vT + ((size_t)(h * 64 + r) << 14) + n0 + c);
      *(uint4*)&vt[r2][c2] = *(const uint4*)(vT + ((size_t)(h * 64 + r2) << 14) + n0 + c2);
    }
    __syncthreads();

    // S^T[64n x 64a] = mfma(K-frag, ag-frag); wave owns n-row-tile w
    f32x4 s[4];
    for (int nt=0;nt<4;nt++) s[nt] = {0.f,0.f,0.f,0.f};
    for (int kk = 0; kk < 64; kk += 32){
      int kb = kk + (l >> 4) * 8;
      bf16x8 kf = *(const bf16x8*)&kt[w*16 + (l & 15)][kb];
      for (int nt=0;nt<4;nt++){
        bf16x8 af = *(const bf16x8*)&ag[nt*16 + (l & 15)][kb];
        s[nt] = mfma16(kf, af, s[nt]);
      }
    }
    // exp2 -> P[a][n] (scale folded into agents); vectorized pack+write
    int nb = w*16 + (l >> 4) * 4;
    for (int nt=0;nt<4;nt++){
      int a = nt*16 + (l & 15);
      uint32_t w0 = cvt_pk_bf16(__builtin_amdgcn_exp2f(s[nt][0]), __builtin_amdgcn_exp2f(s[nt][1]));
      uint32_t w1 = cvt_pk_bf16(__builtin_amdgcn_exp2f(s[nt][2]), __builtin_amdgcn_exp2f(s[nt][3]));
      uint2 o; o.x = w0; o.y = w1;
      *(uint2*)&pt[a][nb] = o;
    }
    __syncthreads();

    // acc2[64a x 64d] += P @ V  (wave owns d-stripe w*16); den via ones-MFMA
    for (int kk = 0; kk < 64; kk += 32){
      int kb = kk + (l >> 4) * 8;
      bf16x8 vf = *(const bf16x8*)&vt[w*16 + (l & 15)][kb];
      for (int mt=0;mt<4;mt++){
        bf16x8 pf = *(const bf16x8*)&pt[mt*16 + (l & 15)][kb];
        acc2[mt] = mfma16(pf, vf, acc2[mt]);
      }
      bf16x8 pw = *(const bf16x8*)&pt[w*16 + (l & 15)][kb];
      accd = mfma16(ones, pw, accd);
    }
  }

  size_t base = ((size_t)(h * 16 + ch) * 512 + a0) * 64;
  for (int mt=0;mt<4;mt++)
    #pragma unroll
    for (int j=0;j<4;j++){
      int a = mt*16 + (l>>4)*4 + j;
      int d = w*16 + (l&15);
      nump[base + (size_t)a*64 + d] = acc2[mt][j];
    }
  if (l < 16) denp[(size_t)(h*16 + ch) * 512 + a0 + w*16 + l] = accd[0];
}

// ---------------- reduce partials -> agent_v transposed [h][d][a] bf16 ----------
__global__ __launch_bounds__(64) void k_agent_reduce(const float* __restrict__ nump, const float* __restrict__ denp,
                                                     u16* __restrict__ avtg){
  int h = blockIdx.x >> 9;
  int a = blockIdx.x & 511;
  int d = threadIdx.x;
  float num = 0.f, den = 0.f;
  for (int c = 0; c < 16; c++){
    num += nump[((size_t)(h * 16 + c) * 512 + a) * 64 + d];
    den += denp[(size_t)(h * 16 + c) * 512 + a];
  }
  avtg[((size_t)h * 64 + d) * 512 + a] = f2bf(num / den);
}

// ---------------- query attention: softmax_a(q*agent^T)*agent_v + v -> atto ------
// grid (256, 8): 64-row q tiles x heads
__global__ __launch_bounds__(256) void k_qattn(const u16* __restrict__ qkv, const u16* __restrict__ agbf,
                                               const u16* __restrict__ avtg, u16* __restrict__ atto){
  int n0 = blockIdx.x * 64;
  int h  = blockIdx.y;
  __shared__ u16 qt[64][72];
  __shared__ u16 ag[64][72];
  __shared__ u16 avt[64][72];   // agent_v^T [d][a-tile]
  __shared__ u16 pt[64][72];    // P [n][a-tile]
  __shared__ float dnf[64];
  int t = threadIdx.x, w = t >> 6, l = t & 63;

  for (int i = 0; i < 2; i++){
    int flat = t + 256 * i;
    int r = flat >> 3, c = (flat & 7) * 8;
    *(uint4*)&qt[r][c] = *(const uint4*)(qkv + (size_t)(n0 + r) * 1536 + h * 64 + c);
  }

  bf16x8 ones;
  for (int i = 0; i < 8; i++) ones[i] = (short)0x3F80;

  f32x4 acc[4];                  // D[n(4 tiles)][d-stripe w*16]
  for (int i=0;i<4;i++) acc[i] = {0.f,0.f,0.f,0.f};
  f32x4 accd = {0.f,0.f,0.f,0.f};// den[n], wave owns n-stripe w*16

  for (int at = 0; at < 8; at++){
    int a0 = at * 64;
    __syncthreads();             // prev readers of ag/avt/pt done
    for (int i = 0; i < 2; i++){
      int flat = t + 256 * i;
      int r = flat >> 3, c = (flat & 7) * 8;
      *(uint4*)&ag[r][c]  = *(const uint4*)(agbf + (size_t)(h * 512 + a0 + r) * 64 + c);
      *(uint4*)&avt[r][c] = *(const uint4*)(avtg + (size_t)(h * 64 + r) * 512 + a0 + c);
    }
    __syncthreads();

    // S^T[a-stripe w x 64n] = mfma(ag-frag, q-frag)
    f32x4 s[4];
    for (int nt=0;nt<4;nt++) s[nt] = {0.f,0.f,0.f,0.f};
    for (int kk = 0; kk < 64; kk += 32){
      int kb = kk + (l >> 4) * 8;
      bf16x8 af = *(const bf16x8*)&ag[w*16 + (l & 15)][kb];
      for (int nt=0;nt<4;nt++){
        bf16x8 qf = *(const bf16x8*)&qt[nt*16 + (l & 15)][kb];
        s[nt] = mfma16(af, qf, s[nt]);
      }
    }
    // exp2 -> P[n][a] (4 consecutive a per lane)
    int ab = w*16 + (l >> 4) * 4;
    for (int nt=0;nt<4;nt++){
      int n = nt*16 + (l & 15);
      uint32_t w0 = cvt_pk_bf16(__builtin_amdgcn_exp2f(s[nt][0]), __builtin_amdgcn_exp2f(s[nt][1]));
      uint32_t w1 = cvt_pk_bf16(__builtin_amdgcn_exp2f(s[nt][2]), __builtin_amdgcn_exp2f(s[nt][3]));
      uint2 o; o.x = w0; o.y = w1;
      *(uint2*)&pt[n][ab] = o;
    }
    __syncthreads();

    // acc[64n x 64d] += P @ agent_v (wave owns d-stripe w*16); den via ones-MFMA
    for (int kk = 0; kk < 64; kk += 32){
      int kb = kk + (l >> 4) * 8;
      bf16x8 vf = *(const bf16x8*)&avt[w*16 + (l & 15)][kb];
      for (int mt=0;mt<4;mt++){
        bf16x8 pf = *(const bf16x8*)&pt[mt*16 + (l & 15)][kb];
        acc[mt] = mfma16(pf, vf, acc[mt]);
      }
      bf16x8 pw = *(const bf16x8*)&pt[w*16 + (l & 15)][kb];
      accd = mfma16(ones, pw, accd);
    }
  }

  if (l < 16) dnf[w*16 + l] = accd[0];
  __syncthreads();
  if (t < 64) dnf[t] = __builtin_amdgcn_rcpf(dnf[t]);
  __syncthreads();

  // epilogue: out = acc * (1/den) + v
  int d = w*16 + (l & 15);
  for (int mt=0;mt<4;mt++){
    #pragma unroll
    for (int j=0;j<4;j++){
      int n = mt*16 + (l>>4)*4 + j;
      float v = bf2f(qkv[(size_t)(n0 + n) * 1536 + 1024 + h * 64 + d]);
      atto[(size_t)(n0 + n) * 512 + h * 64 + d] = f2bf(acc[mt][j] * dnf[n] + v);
    }
  }
}

extern "C" void kernel_launch(void* const* d_in, const int* in_sizes, int n_in,
                              void* d_out, int out_size, void* d_ws, size_t ws_size,
                              hipStream_t stream) {
  const float* x     = (const float*)d_in[0];
  const float* gamma = (const float*)d_in[1];
  const float* beta  = (const float*)d_in[2];
  const float* w_qkv = (const float*)d_in[3];
  const float* agent = (const float*)d_in[4];
  const float* w_out = (const float*)d_in[5];
  const float* b_out = (const float*)d_in[6];
  float* y = (float*)d_out;

  char* ws = (char*)d_ws;
  // byte offsets (all 16B aligned)
  u16*   xn    = (u16*)  (ws + 0);            // 16384*512  bf16 = 16,777,216  (dead after qkv GEMM)
  u16*   vT    = (u16*)  (ws + 0);            // reuses xn: 8*64*16384 bf16 = 16,777,216
  u16*   qkv   = (u16*)  (ws + 16777216);     // 16384*1536 bf16 = 50,331,648
  u16*   wqkvt = (u16*)  (ws + 67108864);     // 1536*512   bf16 =  1,572,864
  u16*   woutt = (u16*)  (ws + 68681728);     // 512*512    bf16 =    524,288
  u16*   agbf  = (u16*)  (ws + 69206016);     // 8*512*64   bf16 =    524,288  (pre-scaled by 0.125*log2e)
  u16*   avtg  = (u16*)  (ws + 69730304);     // 8*64*512   bf16 =    524,288
  u16*   atto  = (u16*)  (ws + 70254592);     // 16384*512  bf16 = 16,777,216
  float* nump  = (float*)(ws + 87031808);     // 8*16*512*64 f32 = 16,777,216
  float* denp  = (float*)(ws + 103809024);    // 8*16*512    f32 =    262,144

  // scale = (1/sqrt(64)) * log2(e), folded into agent so exp(s*scale) == exp2(S')
  k_conv_bf   <<<dim3(256),     dim3(256), 0, stream>>>(agent, agbf, 8*512*64, 0.125f * 1.44269504089f);
  k_transp    <<<dim3(24, 8),   dim3(256), 0, stream>>>(w_qkv, wqkvt, 512, 1536);
  k_transp    <<<dim3(8, 8),    dim3(256), 0, stream>>>(w_out, woutt, 512, 512);
  k_ln        <<<dim3(16384),   dim3(128), 0, stream>>>(x, gamma, beta, xn);
  k_gemm_qkv  <<<dim3(128, 12), dim3(256), 0, stream>>>(xn, wqkvt, qkv);
  k_transp_v  <<<dim3(256, 8),  dim3(256), 0, stream>>>(qkv, vT);
  k_agent_agg <<<dim3(1024),    dim3(256), 0, stream>>>(agbf, qkv, vT, nump, denp);
  k_agent_reduce<<<dim3(4096),  dim3(64),  0, stream>>>(nump, denp, avtg);
  k_qattn     <<<dim3(256, 8),  dim3(256), 0, stream>>>(qkv, agbf, avtg, atto);
  k_gemm_out  <<<dim3(128, 4),  dim3(256), 0, stream>>>(atto, woutt, x, b_out, y);
}

// Round 6
// 167.635 us; speedup vs baseline: 1.0863x; 1.0863x over previous
//
#include <hip/hip_runtime.h>
#include <stdint.h>

typedef unsigned short u16;
typedef __attribute__((ext_vector_type(8))) short bf16x8;
typedef __attribute__((ext_vector_type(4))) float f32x4;

__device__ __forceinline__ float bf2f(u16 u){
  union { uint32_t i; float f; } v; v.i = ((uint32_t)u) << 16; return v.f;
}
__device__ __forceinline__ u16 f2bf(float f){
  union { float fl; uint32_t i; } v; v.fl = f;
  uint32_t r = v.i + 0x7FFFu + ((v.i >> 16) & 1u);
  return (u16)(r >> 16);
}
__device__ __forceinline__ uint32_t cvt_pk_bf16(float lo, float hi){
  uint32_t r;
  asm("v_cvt_pk_bf16_f32 %0, %1, %2" : "=v"(r) : "v"(lo), "v"(hi));
  return r;
}
__device__ __forceinline__ f32x4 mfma16(bf16x8 a, bf16x8 b, f32x4 c){
  return __builtin_amdgcn_mfma_f32_16x16x32_bf16(a, b, c, 0, 0, 0);
}
// async global->LDS, 16 B per lane; LDS dest is wave-uniform base + lane*16
__device__ __forceinline__ void gload16(const u16* g, u16* l){
  __builtin_amdgcn_global_load_lds((const __attribute__((address_space(1))) void*)g,
                                   (__attribute__((address_space(3))) void*)l, 16, 0, 0);
}

// ---------------- elementwise convert f32 -> bf16 (with scale fold) ----------------
__global__ __launch_bounds__(256) void k_conv_bf(const float* __restrict__ in, u16* __restrict__ out, int n, float scale){
  int i = (blockIdx.x * 256 + threadIdx.x) * 4;
  if (i >= n) return;
  float4 v = *(const float4*)(in + i);
  ushort4 o; o.x=f2bf(v.x*scale); o.y=f2bf(v.y*scale); o.z=f2bf(v.z*scale); o.w=f2bf(v.w*scale);
  *(ushort4*)(out + i) = o;
}

// ---------- transpose + convert: in[R][C] f32 -> out[C][R] bf16 ----------
__global__ __launch_bounds__(256) void k_transp(const float* __restrict__ in, u16* __restrict__ out, int R, int C){
  __shared__ u16 tile[64][68];
  int c0 = blockIdx.x * 64, r0 = blockIdx.y * 64;
  int tr = threadIdx.x >> 4;           // 0..15
  int tc = (threadIdx.x & 15) * 4;     // 0..60
  for (int rr = 0; rr < 4; rr++){
    int r = rr * 16 + tr;
    float4 v = *(const float4*)(in + (size_t)(r0 + r) * C + c0 + tc);
    ushort4 o; o.x=f2bf(v.x); o.y=f2bf(v.y); o.z=f2bf(v.z); o.w=f2bf(v.w);
    *(ushort4*)&tile[r][tc] = o;
  }
  __syncthreads();
  for (int rr = 0; rr < 4; rr++){
    int oc = rr * 16 + tr;             // original col = out row
    ushort4 o;
    o.x = tile[tc+0][oc]; o.y = tile[tc+1][oc]; o.z = tile[tc+2][oc]; o.w = tile[tc+3][oc];
    *(ushort4*)(out + (size_t)(c0 + oc) * R + r0 + tc) = o;
  }
}

// ---------- transpose V part of qkv (bf16) -> vT[8*64][16384] ----------
__global__ __launch_bounds__(256) void k_transp_v(const u16* __restrict__ qkv, u16* __restrict__ vT){
  __shared__ u16 tile[64][68];
  int n0 = blockIdx.x * 64;            // n tile
  int c0 = blockIdx.y * 64;            // (h*64+d) tile
  int tr = threadIdx.x >> 4;
  int tc = (threadIdx.x & 15) * 4;
  for (int rr = 0; rr < 4; rr++){
    int r = rr * 16 + tr;
    ushort4 v = *(const ushort4*)(qkv + (size_t)(n0 + r) * 1536 + 1024 + c0 + tc);
    *(ushort4*)&tile[r][tc] = v;
  }
  __syncthreads();
  for (int rr = 0; rr < 4; rr++){
    int oc = rr * 16 + tr;
    ushort4 o;
    o.x = tile[tc+0][oc]; o.y = tile[tc+1][oc]; o.z = tile[tc+2][oc]; o.w = tile[tc+3][oc];
    *(ushort4*)(vT + (size_t)(c0 + oc) * 16384 + n0 + tc) = o;
  }
}

// ---------------- LayerNorm: x[16384][512] f32 -> xn bf16 ----------------
__global__ __launch_bounds__(128) void k_ln(const float* __restrict__ x, const float* __restrict__ g,
                                            const float* __restrict__ b, u16* __restrict__ xn){
  int row = blockIdx.x;
  int t = threadIdx.x;
  float4 v = *(const float4*)(x + (size_t)row * 512 + t * 4);
  float s = v.x + v.y + v.z + v.w;
  float q = v.x*v.x + v.y*v.y + v.z*v.z + v.w*v.w;
  for (int o = 32; o > 0; o >>= 1){ s += __shfl_down(s, o); q += __shfl_down(q, o); }
  __shared__ float red[4];
  if ((t & 63) == 0){ red[(t >> 6) * 2] = s; red[(t >> 6) * 2 + 1] = q; }
  __syncthreads();
  float mu  = (red[0] + red[2]) * (1.0f/512.0f);
  float var = (red[1] + red[3]) * (1.0f/512.0f) - mu * mu;
  float rs = rsqrtf(var + 1e-5f);
  float4 gv = *(const float4*)(g + t * 4);
  float4 bv = *(const float4*)(b + t * 4);
  ushort4 o;
  o.x = f2bf((v.x - mu) * rs * gv.x + bv.x);
  o.y = f2bf((v.y - mu) * rs * gv.y + bv.y);
  o.z = f2bf((v.z - mu) * rs * gv.z + bv.z);
  o.w = f2bf((v.w - mu) * rs * gv.w + bv.w);
  *(ushort4*)(xn + (size_t)row * 512 + t * 4) = o;
}

// ======== 256x128-tile 2-phase GEMM skeleton (8 waves, swizzled LDS) =========
// LDS storage: 16B block position p of row r holds logical block p ^ (r&7).
// gload_lds writes linearly (lane l -> row base+(l>>3), block l&7), so the
// per-lane GLOBAL source pre-applies the same XOR: blkSrc = (l&7) ^ ((l>>3)&7).
// ds_read of logical blk at row ra reads position blk ^ (ra&7) = blk ^ (l&7).

// ------- QKV GEMM: C[16384][1536] = A[16384][512] * Bt[1536][512]^T ----------
__global__ __launch_bounds__(512) void k_gemm_qkv(const u16* __restrict__ A, const u16* __restrict__ Bt,
                                                  u16* __restrict__ C){
  __shared__ u16 aL[2][256 * 64];
  __shared__ u16 bL[2][128 * 64];
  int m0 = blockIdx.x * 256, n0 = blockIdx.y * 128;
  int t = threadIdx.x, w = t >> 6, l = t & 63;
  int wm = (w >> 1) * 64, wn = (w & 1) * 64;   // 4M x 2N wave grid
  int lr = l & 15;
  int blkSrc = (l & 7) ^ ((l >> 3) & 7);
  const u16* gA = A  + (size_t)(m0 + w*8 + (l >> 3)) * 512 + blkSrc * 8;
  const u16* gB = Bt + (size_t)(n0 + w*8 + (l >> 3)) * 512 + blkSrc * 8;
  f32x4 acc[4][4];
  for (int i=0;i<4;i++) for (int j=0;j<4;j++) acc[i][j] = {0.f,0.f,0.f,0.f};

  auto stage = [&](int buf, int k0){
    #pragma unroll
    for (int p = 0; p < 4; p++)
      gload16(gA + (size_t)p*64*512 + k0, &aL[buf][(p*64 + w*8) * 64]);
    #pragma unroll
    for (int p = 0; p < 2; p++)
      gload16(gB + (size_t)p*64*512 + k0, &bL[buf][(p*64 + w*8) * 64]);
  };
  auto comp = [&](const u16* ab, const u16* bb){
    #pragma unroll
    for (int kk = 0; kk < 64; kk += 32){
      int xo = (((l >> 4) + (kk >> 3)) ^ (l & 7)) << 3;  // swizzled 16B-block byte/2 offset
      bf16x8 av[4], bv[4];
      #pragma unroll
      for (int mt=0;mt<4;mt++) av[mt] = *(const bf16x8*)&ab[(wm + mt*16 + lr)*64 + xo];
      #pragma unroll
      for (int nt=0;nt<4;nt++) bv[nt] = *(const bf16x8*)&bb[(wn + nt*16 + lr)*64 + xo];
      #pragma unroll
      for (int mt=0;mt<4;mt++)
        #pragma unroll
        for (int nt=0;nt<4;nt++)
          acc[mt][nt] = mfma16(av[mt], bv[nt], acc[mt][nt]);
    }
  };

  stage(0, 0);
  __syncthreads();                     // buf0 ready (implicit vmcnt(0))
  #pragma unroll
  for (int tk = 0; tk < 8; tk++){
    int cur = tk & 1;
    if (tk < 7) stage(cur ^ 1, (tk + 1) * 64);   // issue next-tile loads early
    comp(&aL[cur][0], &bL[cur][0]);
    __syncthreads();                              // drain + swap
  }

  int rr = (l >> 4) * 4, cc = l & 15;
  for (int mt=0;mt<4;mt++) for (int nt=0;nt<4;nt++)
    for (int j=0;j<4;j++){
      int r = m0 + wm + mt*16 + rr + j;
      int c = n0 + wn + nt*16 + cc;
      C[(size_t)r * 1536 + c] = f2bf(acc[mt][nt][j]);
    }
}

// ------- out GEMM: y = A[16384][512]*Bt[512][512]^T + bias + x (f32) ----------
__global__ __launch_bounds__(512) void k_gemm_out(const u16* __restrict__ A, const u16* __restrict__ Bt,
                                                  const float* __restrict__ x, const float* __restrict__ bias,
                                                  float* __restrict__ y){
  __shared__ u16 aL[2][256 * 64];
  __shared__ u16 bL[2][128 * 64];
  int m0 = blockIdx.x * 256, n0 = blockIdx.y * 128;
  int t = threadIdx.x, w = t >> 6, l = t & 63;
  int wm = (w >> 1) * 64, wn = (w & 1) * 64;
  int lr = l & 15;
  int blkSrc = (l & 7) ^ ((l >> 3) & 7);
  const u16* gA = A  + (size_t)(m0 + w*8 + (l >> 3)) * 512 + blkSrc * 8;
  const u16* gB = Bt + (size_t)(n0 + w*8 + (l >> 3)) * 512 + blkSrc * 8;
  f32x4 acc[4][4];
  for (int i=0;i<4;i++) for (int j=0;j<4;j++) acc[i][j] = {0.f,0.f,0.f,0.f};

  auto stage = [&](int buf, int k0){
    #pragma unroll
    for (int p = 0; p < 4; p++)
      gload16(gA + (size_t)p*64*512 + k0, &aL[buf][(p*64 + w*8) * 64]);
    #pragma unroll
    for (int p = 0; p < 2; p++)
      gload16(gB + (size_t)p*64*512 + k0, &bL[buf][(p*64 + w*8) * 64]);
  };
  auto comp = [&](const u16* ab, const u16* bb){
    #pragma unroll
    for (int kk = 0; kk < 64; kk += 32){
      int xo = (((l >> 4) + (kk >> 3)) ^ (l & 7)) << 3;
      bf16x8 av[4], bv[4];
      #pragma unroll
      for (int mt=0;mt<4;mt++) av[mt] = *(const bf16x8*)&ab[(wm + mt*16 + lr)*64 + xo];
      #pragma unroll
      for (int nt=0;nt<4;nt++) bv[nt] = *(const bf16x8*)&bb[(wn + nt*16 + lr)*64 + xo];
      #pragma unroll
      for (int mt=0;mt<4;mt++)
        #pragma unroll
        for (int nt=0;nt<4;nt++)
          acc[mt][nt] = mfma16(av[mt], bv[nt], acc[mt][nt]);
    }
  };

  stage(0, 0);
  __syncthreads();
  #pragma unroll
  for (int tk = 0; tk < 8; tk++){
    int cur = tk & 1;
    if (tk < 7) stage(cur ^ 1, (tk + 1) * 64);
    comp(&aL[cur][0], &bL[cur][0]);
    __syncthreads();
  }

  int rr = (l >> 4) * 4, cc = l & 15;
  for (int mt=0;mt<4;mt++) for (int nt=0;nt<4;nt++)
    for (int j=0;j<4;j++){
      int r = m0 + wm + mt*16 + rr + j;
      int c = n0 + wn + nt*16 + cc;
      y[(size_t)r * 512 + c] = acc[mt][nt][j] + bias[c] + x[(size_t)r * 512 + c];
    }
}

// ---------------- agent aggregation partials (attn1 + agent_v, no-max softmax) ----
// 1024 blocks; swizzled so the 8 atile-blocks of one (h,chunk) share an XCD.
__global__ __launch_bounds__(256) void k_agent_agg(const u16* __restrict__ agbf, const u16* __restrict__ qkv,
                                                   const u16* __restrict__ vT,
                                                   float* __restrict__ nump, float* __restrict__ denp){
  int L = blockIdx.x;
  int g = (L >> 6) * 8 + (L & 7);      // group = h*16 + ch  (same K/V panel)
  int m = (L >> 3) & 7;                // atile
  int h = g >> 4, ch = g & 15, a0 = m * 64;

  __shared__ u16 ag[64][72];
  __shared__ u16 kt[64][72];
  __shared__ u16 vt[64][72];
  __shared__ u16 pt[64][72];
  int t = threadIdx.x, w = t >> 6, l = t & 63;

  for (int i = 0; i < 2; i++){
    int flat = t + 256 * i;
    int r = flat >> 3, c = (flat & 7) * 8;
    *(uint4*)&ag[r][c] = *(const uint4*)(agbf + (size_t)(h * 512 + a0 + r) * 64 + c);
  }

  bf16x8 ones;
  for (int i = 0; i < 8; i++) ones[i] = (short)0x3F80;

  f32x4 acc2[4];                       // C[a][d], wave owns d-stripe w*16
  for (int i=0;i<4;i++) acc2[i] = {0.f,0.f,0.f,0.f};
  f32x4 accd = {0.f,0.f,0.f,0.f};      // den[a], wave owns a-stripe w*16

  for (int sub = 0; sub < 16; sub++){
    int n0 = ch * 1024 + sub * 64;
    __syncthreads();                   // protect kt/vt/pt from previous readers
    {
      int flat = t;
      int r = flat >> 3, c = (flat & 7) * 8;
      *(uint4*)&kt[r][c] = *(const uint4*)(qkv + (size_t)(n0 + r) * 1536 + 512 + h * 64 + c);
      int flat2 = t + 256;
      int r2 = flat2 >> 3, c2 = (flat2 & 7) * 8;
      *(uint4*)&kt[r2][c2] = *(const uint4*)(qkv + (size_t)(n0 + r2) * 1536 + 512 + h * 64 + c2);
      *(uint4*)&vt[r][c]   = *(const uint4*)(vT + ((size_t)(h * 64 + r) << 14) + n0 + c);
      *(uint4*)&vt[r2][c2] = *(const uint4*)(vT + ((size_t)(h * 64 + r2) << 14) + n0 + c2);
    }
    __syncthreads();

    // S^T[64n x 64a] = mfma(K-frag, ag-frag); wave owns n-row-tile w
    f32x4 s[4];
    for (int nt=0;nt<4;nt++) s[nt] = {0.f,0.f,0.f,0.f};
    for (int kk = 0; kk < 64; kk += 32){
      int kb = kk + (l >> 4) * 8;
      bf16x8 kf = *(const bf16x8*)&kt[w*16 + (l & 15)][kb];
      for (int nt=0;nt<4;nt++){
        bf16x8 af = *(const bf16x8*)&ag[nt*16 + (l & 15)][kb];
        s[nt] = mfma16(kf, af, s[nt]);
      }
    }
    // exp2 -> P[a][n] (scale folded into agents); vectorized pack+write
    int nb = w*16 + (l >> 4) * 4;
    for (int nt=0;nt<4;nt++){
      int a = nt*16 + (l & 15);
      uint32_t w0 = cvt_pk_bf16(__builtin_amdgcn_exp2f(s[nt][0]), __builtin_amdgcn_exp2f(s[nt][1]));
      uint32_t w1 = cvt_pk_bf16(__builtin_amdgcn_exp2f(s[nt][2]), __builtin_amdgcn_exp2f(s[nt][3]));
      uint2 o; o.x = w0; o.y = w1;
      *(uint2*)&pt[a][nb] = o;
    }
    __syncthreads();

    // acc2[64a x 64d] += P @ V  (wave owns d-stripe w*16); den via ones-MFMA
    for (int kk = 0; kk < 64; kk += 32){
      int kb = kk + (l >> 4) * 8;
      bf16x8 vf = *(const bf16x8*)&vt[w*16 + (l & 15)][kb];
      for (int mt=0;mt<4;mt++){
        bf16x8 pf = *(const bf16x8*)&pt[mt*16 + (l & 15)][kb];
        acc2[mt] = mfma16(pf, vf, acc2[mt]);
      }
      bf16x8 pw = *(const bf16x8*)&pt[w*16 + (l & 15)][kb];
      accd = mfma16(ones, pw, accd);
    }
  }

  size_t base = ((size_t)(h * 16 + ch) * 512 + a0) * 64;
  for (int mt=0;mt<4;mt++)
    #pragma unroll
    for (int j=0;j<4;j++){
      int a = mt*16 + (l>>4)*4 + j;
      int d = w*16 + (l&15);
      nump[base + (size_t)a*64 + d] = acc2[mt][j];
    }
  if (l < 16) denp[(size_t)(h*16 + ch) * 512 + a0 + w*16 + l] = accd[0];
}

// ---------------- reduce partials -> agent_v transposed [h][d][a] bf16 ----------
__global__ __launch_bounds__(64) void k_agent_reduce(const float* __restrict__ nump, const float* __restrict__ denp,
                                                     u16* __restrict__ avtg){
  int h = blockIdx.x >> 9;
  int a = blockIdx.x & 511;
  int d = threadIdx.x;
  float num = 0.f, den = 0.f;
  for (int c = 0; c < 16; c++){
    num += nump[((size_t)(h * 16 + c) * 512 + a) * 64 + d];
    den += denp[(size_t)(h * 16 + c) * 512 + a];
  }
  avtg[((size_t)h * 64 + d) * 512 + a] = f2bf(num / den);
}

// ---------------- query attention: softmax_a(q*agent^T)*agent_v + v -> atto ------
// grid (256, 8): 64-row q tiles x heads
__global__ __launch_bounds__(256) void k_qattn(const u16* __restrict__ qkv, const u16* __restrict__ agbf,
                                               const u16* __restrict__ avtg, u16* __restrict__ atto){
  int n0 = blockIdx.x * 64;
  int h  = blockIdx.y;
  __shared__ u16 qt[64][72];
  __shared__ u16 ag[64][72];
  __shared__ u16 avt[64][72];   // agent_v^T [d][a-tile]
  __shared__ u16 pt[64][72];    // P [n][a-tile]
  __shared__ float dnf[64];
  int t = threadIdx.x, w = t >> 6, l = t & 63;

  for (int i = 0; i < 2; i++){
    int flat = t + 256 * i;
    int r = flat >> 3, c = (flat & 7) * 8;
    *(uint4*)&qt[r][c] = *(const uint4*)(qkv + (size_t)(n0 + r) * 1536 + h * 64 + c);
  }

  bf16x8 ones;
  for (int i = 0; i < 8; i++) ones[i] = (short)0x3F80;

  f32x4 acc[4];                  // D[n(4 tiles)][d-stripe w*16]
  for (int i=0;i<4;i++) acc[i] = {0.f,0.f,0.f,0.f};
  f32x4 accd = {0.f,0.f,0.f,0.f};// den[n], wave owns n-stripe w*16

  for (int at = 0; at < 8; at++){
    int a0 = at * 64;
    __syncthreads();             // prev readers of ag/avt/pt done
    for (int i = 0; i < 2; i++){
      int flat = t + 256 * i;
      int r = flat >> 3, c = (flat & 7) * 8;
      *(uint4*)&ag[r][c]  = *(const uint4*)(agbf + (size_t)(h * 512 + a0 + r) * 64 + c);
      *(uint4*)&avt[r][c] = *(const uint4*)(avtg + (size_t)(h * 64 + r) * 512 + a0 + c);
    }
    __syncthreads();

    // S^T[a-stripe w x 64n] = mfma(ag-frag, q-frag)
    f32x4 s[4];
    for (int nt=0;nt<4;nt++) s[nt] = {0.f,0.f,0.f,0.f};
    for (int kk = 0; kk < 64; kk += 32){
      int kb = kk + (l >> 4) * 8;
      bf16x8 af = *(const bf16x8*)&ag[w*16 + (l & 15)][kb];
      for (int nt=0;nt<4;nt++){
        bf16x8 qf = *(const bf16x8*)&qt[nt*16 + (l & 15)][kb];
        s[nt] = mfma16(af, qf, s[nt]);
      }
    }
    // exp2 -> P[n][a] (4 consecutive a per lane)
    int ab = w*16 + (l >> 4) * 4;
    for (int nt=0;nt<4;nt++){
      int n = nt*16 + (l & 15);
      uint32_t w0 = cvt_pk_bf16(__builtin_amdgcn_exp2f(s[nt][0]), __builtin_amdgcn_exp2f(s[nt][1]));
      uint32_t w1 = cvt_pk_bf16(__builtin_amdgcn_exp2f(s[nt][2]), __builtin_amdgcn_exp2f(s[nt][3]));
      uint2 o; o.x = w0; o.y = w1;
      *(uint2*)&pt[n][ab] = o;
    }
    __syncthreads();

    // acc[64n x 64d] += P @ agent_v (wave owns d-stripe w*16); den via ones-MFMA
    for (int kk = 0; kk < 64; kk += 32){
      int kb = kk + (l >> 4) * 8;
      bf16x8 vf = *(const bf16x8*)&avt[w*16 + (l & 15)][kb];
      for (int mt=0;mt<4;mt++){
        bf16x8 pf = *(const bf16x8*)&pt[mt*16 + (l & 15)][kb];
        acc[mt] = mfma16(pf, vf, acc[mt]);
      }
      bf16x8 pw = *(const bf16x8*)&pt[w*16 + (l & 15)][kb];
      accd = mfma16(ones, pw, accd);
    }
  }

  if (l < 16) dnf[w*16 + l] = accd[0];
  __syncthreads();
  if (t < 64) dnf[t] = __builtin_amdgcn_rcpf(dnf[t]);
  __syncthreads();

  // epilogue: out = acc * (1/den) + v
  int d = w*16 + (l & 15);
  for (int mt=0;mt<4;mt++){
    #pragma unroll
    for (int j=0;j<4;j++){
      int n = mt*16 + (l>>4)*4 + j;
      float v = bf2f(qkv[(size_t)(n0 + n) * 1536 + 1024 + h * 64 + d]);
      atto[(size_t)(n0 + n) * 512 + h * 64 + d] = f2bf(acc[mt][j] * dnf[n] + v);
    }
  }
}

extern "C" void kernel_launch(void* const* d_in, const int* in_sizes, int n_in,
                              void* d_out, int out_size, void* d_ws, size_t ws_size,
                              hipStream_t stream) {
  const float* x     = (const float*)d_in[0];
  const float* gamma = (const float*)d_in[1];
  const float* beta  = (const float*)d_in[2];
  const float* w_qkv = (const float*)d_in[3];
  const float* agent = (const float*)d_in[4];
  const float* w_out = (const float*)d_in[5];
  const float* b_out = (const float*)d_in[6];
  float* y = (float*)d_out;

  char* ws = (char*)d_ws;
  // byte offsets (all 16B aligned)
  u16*   xn    = (u16*)  (ws + 0);            // 16384*512  bf16 = 16,777,216  (dead after qkv GEMM)
  u16*   vT    = (u16*)  (ws + 0);            // reuses xn: 8*64*16384 bf16 = 16,777,216
  u16*   qkv   = (u16*)  (ws + 16777216);     // 16384*1536 bf16 = 50,331,648
  u16*   wqkvt = (u16*)  (ws + 67108864);     // 1536*512   bf16 =  1,572,864
  u16*   woutt = (u16*)  (ws + 68681728);     // 512*512    bf16 =    524,288
  u16*   agbf  = (u16*)  (ws + 69206016);     // 8*512*64   bf16 =    524,288  (pre-scaled by 0.125*log2e)
  u16*   avtg  = (u16*)  (ws + 69730304);     // 8*64*512   bf16 =    524,288
  u16*   atto  = (u16*)  (ws + 70254592);     // 16384*512  bf16 = 16,777,216
  float* nump  = (float*)(ws + 87031808);     // 8*16*512*64 f32 = 16,777,216
  float* denp  = (float*)(ws + 103809024);    // 8*16*512    f32 =    262,144

  // scale = (1/sqrt(64)) * log2(e), folded into agent so exp(s*scale) == exp2(S')
  k_conv_bf   <<<dim3(256),     dim3(256), 0, stream>>>(agent, agbf, 8*512*64, 0.125f * 1.44269504089f);
  k_transp    <<<dim3(24, 8),   dim3(256), 0, stream>>>(w_qkv, wqkvt, 512, 1536);
  k_transp    <<<dim3(8, 8),    dim3(256), 0, stream>>>(w_out, woutt, 512, 512);
  k_ln        <<<dim3(16384),   dim3(128), 0, stream>>>(x, gamma, beta, xn);
  k_gemm_qkv  <<<dim3(64, 12),  dim3(512), 0, stream>>>(xn, wqkvt, qkv);
  k_transp_v  <<<dim3(256, 8),  dim3(256), 0, stream>>>(qkv, vT);
  k_agent_agg <<<dim3(1024),    dim3(256), 0, stream>>>(agbf, qkv, vT, nump, denp);
  k_agent_reduce<<<dim3(4096),  dim3(64),  0, stream>>>(nump, denp, avtg);
  k_qattn     <<<dim3(256, 8),  dim3(256), 0, stream>>>(qkv, agbf, avtg, atto);
  k_gemm_out  <<<dim3(64, 4),   dim3(512), 0, stream>>>(atto, woutt, x, b_out, y);
}